// Round 1
// baseline (230661.938 us; speedup 1.0000x reference)
//
#include <hip/hip_runtime.h>
#include <hip/hip_cooperative_groups.h>

namespace cg = cooperative_groups;

// Model dims
constexpr int TSTEPS = 2048;
constexpr int G = 256;   // workgroups (1 per CU)
constexpr int B = 512;   // threads per WG (8 waves/CU)

// ws layout (float offsets)
constexpr size_t OFF_X512 = 0;            // [512]  linear1 output
constexpr size_t OFF_OUT  = 512;          // [512]  model output (prev step)
constexpr size_t OFF_H1   = 1024;         // [2][2048]
constexpr size_t OFF_H2   = 1024 + 4096;  // [2][2048]
constexpr int STATE_FLOATS = 1024 + 8192; // 9216

// packed weight blobs (float4 counts)
constexpr size_t NA  = (size_t)G * 24 * B;   // FF1: 2x3072x2048 fp32
constexpr size_t NB  = (size_t)G * 32 * B;   // FF2: 2x4096x2048
constexpr size_t NC2 = (size_t)128 * 4 * B;  // W2: 2048x512
constexpr size_t NC1 = (size_t)128 * 5 * B;  // W1: 2560x512
constexpr size_t OFF_BLOBA  = 9216;
constexpr size_t OFF_BLOBB  = OFF_BLOBA  + NA  * 4;
constexpr size_t OFF_BLOBC2 = OFF_BLOBB  + NB  * 4;
constexpr size_t OFF_BLOBC1 = OFF_BLOBC2 + NC2 * 4;
constexpr size_t WS_FLOATS  = OFF_BLOBC1 + NC1 * 4;   // ~31.7M floats = ~121 MB

// ---------------- pack kernels (one-time per launch) ----------------
// Main-loop thread mapping (FF phases): tid = c(0..7) + 8*jk + 16*s(0..31)
// blob[wg][u][tid] = float4 of 4 consecutive rows i0..i0+3 of column o=wg*8+c.
__global__ void pack_ab(const float* __restrict__ J, const float* __restrict__ K,
                        float4* __restrict__ blob, int rpt, int nU)
{
    size_t id = (size_t)blockIdx.x * 256 + threadIdx.x;
    size_t total = (size_t)G * nU * B;
    if (id >= total) return;
    int tid = (int)(id & (B - 1));
    int u   = (int)((id >> 9) % nU);
    int wg  = (int)(id / ((size_t)B * nU));
    int c = tid & 7, jk = (tid >> 3) & 1, s = tid >> 4;
    int o = wg * 8 + c;
    int i0 = s * rpt + u * 4;
    const float* W = (jk ? K : J) + (size_t)i0 * 2048 + o;
    blob[id] = make_float4(W[0], W[2048], W[4096], W[6144]);
}

// Phase-C mapping: tid = c(0..3) + 4*s(0..127), col o = wg*4 + c
__global__ void pack_c(const float* __restrict__ W, float4* __restrict__ blob,
                       int fanOut, int rpt, int nU)
{
    size_t id = (size_t)blockIdx.x * 256 + threadIdx.x;
    size_t total = (size_t)128 * nU * B;
    if (id >= total) return;
    int tid = (int)(id & (B - 1));
    int u   = (int)((id >> 9) % nU);
    int wg  = (int)(id / ((size_t)B * nU));
    int c = tid & 3, s = tid >> 2;
    int o = wg * 4 + c;
    int i0 = s * rpt + u * 4;
    const float* p = W + (size_t)i0 * fanOut + o;
    blob[id] = make_float4(p[0], p[fanOut], p[2 * fanOut], p[3 * fanOut]);
}

// ---------------- phase helpers ----------------
__device__ __forceinline__ float sigmoidf_(float d) {
    return 1.f / (1.f + __expf(-d));
}

// FF phase: c = [p0 (n0 floats), hcur (2048)]; 8 cols/WG, j&k; h update.
template<bool PACKED, int NU, int RPT>
__device__ __forceinline__ void phase_ff(
    int wg, int tid,
    const float* __restrict__ Jw, const float* __restrict__ Kw,
    const float* __restrict__ Jb_, const float* __restrict__ Kb_,
    const float4* __restrict__ blob,
    const float* __restrict__ p0, int n0,
    const float* __restrict__ hcur, float* __restrict__ hnxt,
    float* ldsC, float* red, float* jkb)
{
    const int c = tid & 7, jk = (tid >> 3) & 1, s = tid >> 4;
    const int o = wg * 8 + c;
    const int fanIn = n0 + 2048;

    float4 wreg[PACKED ? NU : 1];
    if constexpr (PACKED) {
        const float4* bp = blob + (size_t)wg * NU * B + tid;
#pragma unroll
        for (int u = 0; u < NU; ++u) wreg[u] = bp[(size_t)u * B];
    }
    // stage activation vector into LDS (float4, coalesced)
    for (int i = tid * 4; i < fanIn; i += B * 4) {
        float4 v = (i < n0) ? *(const float4*)(p0 + i)
                            : *(const float4*)(hcur + (i - n0));
        *(float4*)(ldsC + i) = v;
    }
    __syncthreads();

    float acc;
    if constexpr (PACKED) {
        const float* cp = ldsC + s * RPT;
        float4 a4 = make_float4(0.f, 0.f, 0.f, 0.f);
#pragma unroll
        for (int u = 0; u < NU; ++u) {
            float4 cc = *(const float4*)(cp + u * 4);
            a4.x = fmaf(wreg[u].x, cc.x, a4.x);
            a4.y = fmaf(wreg[u].y, cc.y, a4.y);
            a4.z = fmaf(wreg[u].z, cc.z, a4.z);
            a4.w = fmaf(wreg[u].w, cc.w, a4.w);
        }
        acc = (a4.x + a4.y) + (a4.z + a4.w);
    } else {
        const float* __restrict__ W = jk ? Kw : Jw;
        const float* __restrict__ Wp = W + (size_t)(s * RPT) * 2048 + o;
        const float* cp = ldsC + s * RPT;
        float a0 = 0.f, a1 = 0.f;
#pragma unroll 8
        for (int r = 0; r < RPT; r += 2) {
            a0 = fmaf(cp[r],     Wp[(size_t)r * 2048],       a0);
            a1 = fmaf(cp[r + 1], Wp[(size_t)(r + 1) * 2048], a1);
        }
        acc = a0 + a1;
    }
    // reduce over s: bits 4,5 in-wave, then 8 waves via LDS
    acc += __shfl_xor(acc, 16);
    acc += __shfl_xor(acc, 32);
    const int wv = tid >> 6, lane = tid & 63;
    if (lane < 16) red[wv * 16 + lane] = acc;
    __syncthreads();
    if (tid < 16) {
        float d = 0.f;
#pragma unroll
        for (int w = 0; w < 8; ++w) d += red[w * 16 + tid];
        const int cc = tid & 7;
        d += (tid >= 8) ? Kb_[wg * 8 + cc] : Jb_[wg * 8 + cc];
        jkb[tid] = sigmoidf_(d);
    }
    __syncthreads();
    if (tid < 8) {
        float j = jkb[tid], k = jkb[8 + tid];
        float h = ldsC[n0 + wg * 8 + tid];   // old h value
        hnxt[wg * 8 + tid] = fmaf(j, 1.f - h, (1.f - k) * h);
    }
}

// Phase C: WGs 0..127 -> linear2(h2')+sigmoid -> out; WGs 128..255 -> linear1([h2', X[t+1]]) -> x512
template<bool PACKED>
__device__ __forceinline__ void phase_c(
    int wg, int tid,
    const float* __restrict__ W2w, const float* __restrict__ b2v,
    const float* __restrict__ W1w, const float* __restrict__ b1v,
    const float4* __restrict__ blobC2, const float4* __restrict__ blobC1,
    const float* __restrict__ h2r, const float* __restrict__ X, int xrow,
    bool doOut, int outrow, bool doLin1,
    float* __restrict__ xb, float* __restrict__ ob, float* __restrict__ out_g,
    float* ldsC, float* red)
{
    const int c = tid & 3, s = tid >> 2;
    if (wg < 128) {
        if (!doOut) return;
        const int o = wg * 4 + c;
        float4 wreg[PACKED ? 4 : 1];
        if constexpr (PACKED) {
            const float4* bp = blobC2 + (size_t)wg * 4 * B + tid;
#pragma unroll
            for (int u = 0; u < 4; ++u) wreg[u] = bp[(size_t)u * B];
        }
        for (int i = tid * 4; i < 2048; i += B * 4)
            *(float4*)(ldsC + i) = *(const float4*)(h2r + i);
        __syncthreads();
        float acc = 0.f;
        if constexpr (PACKED) {
            const float* cp = ldsC + s * 16;
            float4 a4 = make_float4(0.f, 0.f, 0.f, 0.f);
#pragma unroll
            for (int u = 0; u < 4; ++u) {
                float4 cc = *(const float4*)(cp + u * 4);
                a4.x = fmaf(wreg[u].x, cc.x, a4.x);
                a4.y = fmaf(wreg[u].y, cc.y, a4.y);
                a4.z = fmaf(wreg[u].z, cc.z, a4.z);
                a4.w = fmaf(wreg[u].w, cc.w, a4.w);
            }
            acc = (a4.x + a4.y) + (a4.z + a4.w);
        } else {
            const float* Wp = W2w + (size_t)(s * 16) * 512 + o;
            const float* cp = ldsC + s * 16;
#pragma unroll
            for (int r = 0; r < 16; ++r) acc = fmaf(cp[r], Wp[(size_t)r * 512], acc);
        }
        acc += __shfl_xor(acc, 4);  acc += __shfl_xor(acc, 8);
        acc += __shfl_xor(acc, 16); acc += __shfl_xor(acc, 32);
        const int wv = tid >> 6, lane = tid & 63;
        if (lane < 4) red[wv * 4 + lane] = acc;
        __syncthreads();
        if (tid < 4) {
            float d = b2v[wg * 4 + tid];
#pragma unroll
            for (int w = 0; w < 8; ++w) d += red[w * 4 + tid];
            float sg = sigmoidf_(d);
            ob[wg * 4 + tid] = sg;
            out_g[(size_t)outrow * 512 + wg * 4 + tid] = sg;
        }
    } else {
        if (!doLin1) return;
        const int wg2 = wg - 128;
        const int o = wg2 * 4 + c;
        float4 wreg[PACKED ? 5 : 1];
        if constexpr (PACKED) {
            const float4* bp = blobC1 + (size_t)wg2 * 5 * B + tid;
#pragma unroll
            for (int u = 0; u < 5; ++u) wreg[u] = bp[(size_t)u * B];
        }
        const float* Xr = X + (size_t)xrow * 512;
        for (int i = tid * 4; i < 2560; i += B * 4) {
            float4 v = (i < 2048) ? *(const float4*)(h2r + i)
                                  : *(const float4*)(Xr + (i - 2048));
            *(float4*)(ldsC + i) = v;
        }
        __syncthreads();
        float acc = 0.f;
        if constexpr (PACKED) {
            const float* cp = ldsC + s * 20;
            float4 a4 = make_float4(0.f, 0.f, 0.f, 0.f);
#pragma unroll
            for (int u = 0; u < 5; ++u) {
                float4 cc = *(const float4*)(cp + u * 4);
                a4.x = fmaf(wreg[u].x, cc.x, a4.x);
                a4.y = fmaf(wreg[u].y, cc.y, a4.y);
                a4.z = fmaf(wreg[u].z, cc.z, a4.z);
                a4.w = fmaf(wreg[u].w, cc.w, a4.w);
            }
            acc = (a4.x + a4.y) + (a4.z + a4.w);
        } else {
            const float* Wp = W1w + (size_t)(s * 20) * 512 + o;
            const float* cp = ldsC + s * 20;
#pragma unroll
            for (int r = 0; r < 20; ++r) acc = fmaf(cp[r], Wp[(size_t)r * 512], acc);
        }
        acc += __shfl_xor(acc, 4);  acc += __shfl_xor(acc, 8);
        acc += __shfl_xor(acc, 16); acc += __shfl_xor(acc, 32);
        const int wv = tid >> 6, lane = tid & 63;
        if (lane < 4) red[wv * 4 + lane] = acc;
        __syncthreads();
        if (tid < 4) {
            float d = b1v[wg2 * 4 + tid];
#pragma unroll
            for (int w = 0; w < 8; ++w) d += red[w * 4 + tid];
            xb[wg2 * 4 + tid] = d;   // linear1 has NO activation
        }
    }
}

// ---------------- persistent cooperative kernel ----------------
template<bool PACKED>
__global__ void __launch_bounds__(B)
rnn_kernel(const float* __restrict__ X,
           const float* __restrict__ W1, const float* __restrict__ b1,
           const float* __restrict__ J1W, const float* __restrict__ J1b,
           const float* __restrict__ K1W, const float* __restrict__ K1b,
           const float* __restrict__ J2W, const float* __restrict__ J2b,
           const float* __restrict__ K2W, const float* __restrict__ K2b,
           const float* __restrict__ W2, const float* __restrict__ b2,
           float* out_g, float* ws)
{
    cg::grid_group grid = cg::this_grid();
    const int wg = blockIdx.x, tid = threadIdx.x;
    __shared__ float ldsC[4096];
    __shared__ float red[128];
    __shared__ float jkb[16];

    float* xb  = ws + OFF_X512;
    float* ob  = ws + OFF_OUT;
    float* h1b = ws + OFF_H1;
    float* h2b = ws + OFF_H2;
    const float4* blobA  = (const float4*)(ws + OFF_BLOBA);
    const float4* blobB  = (const float4*)(ws + OFF_BLOBB);
    const float4* blobC2 = (const float4*)(ws + OFF_BLOBC2);
    const float4* blobC1 = (const float4*)(ws + OFF_BLOBC1);

    // zero-init state (ws is poisoned 0xAA before every launch)
    for (int i = wg * B + tid; i < STATE_FLOATS; i += G * B) ws[i] = 0.f;
    grid.sync();

    // pre-loop: x512 for t=0 using ff2_out=0 (h2b[0..2048) is zeros), X row 0
    phase_c<PACKED>(wg, tid, W2, b2, W1, b1, blobC2, blobC1,
                    h2b, X, 0, false, 0, true, xb, ob, out_g, ldsC, red);
    grid.sync();

    for (int t = 0; t < TSTEPS; ++t) {
        const int cur = t & 1, nxt = cur ^ 1;
        // FF1: c = [x512, out, h1cur] -> h1nxt
        phase_ff<PACKED, 24, 96>(wg, tid, J1W, K1W, J1b, K1b, blobA,
                                 ws /* [x512|out] contiguous */, 1024,
                                 h1b + cur * 2048, h1b + nxt * 2048,
                                 ldsC, red, jkb);
        grid.sync();
        // FF2: c = [h1nxt, h2cur] -> h2nxt
        phase_ff<PACKED, 32, 128>(wg, tid, J2W, K2W, J2b, K2b, blobB,
                                  h1b + nxt * 2048, 2048,
                                  h2b + cur * 2048, h2b + nxt * 2048,
                                  ldsC, red, jkb);
        grid.sync();
        // linear2(h2nxt) -> out(t) ; linear1([h2nxt, X[t+1]]) -> x512 for t+1
        phase_c<PACKED>(wg, tid, W2, b2, W1, b1, blobC2, blobC1,
                        h2b + nxt * 2048, X, t + 1, true, t, (t + 1 < TSTEPS),
                        xb, ob, out_g, ldsC, red);
        grid.sync();
    }
}

// ---------------- host ----------------
extern "C" void kernel_launch(void* const* d_in, const int* in_sizes, int n_in,
                              void* d_out, int out_size, void* d_ws, size_t ws_size,
                              hipStream_t stream)
{
    const float* X   = (const float*)d_in[0];
    const float* W1  = (const float*)d_in[1];
    const float* b1  = (const float*)d_in[2];
    const float* J1W = (const float*)d_in[3];
    const float* J1b = (const float*)d_in[4];
    const float* K1W = (const float*)d_in[5];
    const float* K1b = (const float*)d_in[6];
    const float* J2W = (const float*)d_in[7];
    const float* J2b = (const float*)d_in[8];
    const float* K2W = (const float*)d_in[9];
    const float* K2b = (const float*)d_in[10];
    const float* W2  = (const float*)d_in[11];
    const float* b2  = (const float*)d_in[12];
    float* out = (float*)d_out;
    float* ws  = (float*)d_ws;

    const bool packed = ws_size >= WS_FLOATS * sizeof(float);
    if (packed) {
        pack_ab<<<dim3((unsigned)(NA  / 256)), dim3(256), 0, stream>>>(J1W, K1W, (float4*)(ws + OFF_BLOBA), 96, 24);
        pack_ab<<<dim3((unsigned)(NB  / 256)), dim3(256), 0, stream>>>(J2W, K2W, (float4*)(ws + OFF_BLOBB), 128, 32);
        pack_c <<<dim3((unsigned)(NC2 / 256)), dim3(256), 0, stream>>>(W2, (float4*)(ws + OFF_BLOBC2), 512, 16, 4);
        pack_c <<<dim3((unsigned)(NC1 / 256)), dim3(256), 0, stream>>>(W1, (float4*)(ws + OFF_BLOBC1), 512, 20, 5);
    }

    void* args[] = { (void*)&X, (void*)&W1, (void*)&b1,
                     (void*)&J1W, (void*)&J1b, (void*)&K1W, (void*)&K1b,
                     (void*)&J2W, (void*)&J2b, (void*)&K2W, (void*)&K2b,
                     (void*)&W2, (void*)&b2, (void*)&out, (void*)&ws };

    const void* kf = packed ? (const void*)rnn_kernel<true>
                            : (const void*)rnn_kernel<false>;
    hipLaunchCooperativeKernel(kf, dim3(G), dim3(B), args, 0, stream);
}

// Round 8
// 169429.517 us; speedup vs baseline: 1.3614x; 1.3614x over previous
//
#include <hip/hip_runtime.h>
#include <hip/hip_cooperative_groups.h>

namespace cg = cooperative_groups;

// Model dims
constexpr int TSTEPS = 2048;
constexpr int G = 256;   // workgroups (1 per CU)
constexpr int B = 512;   // threads per WG (8 waves/CU)

// ws layout (float offsets)
constexpr size_t OFF_X512 = 0;            // [512]  linear1 output
constexpr size_t OFF_OUT  = 512;          // [512]  model output (prev step)
constexpr size_t OFF_H1   = 1024;         // [2][2048]
constexpr size_t OFF_H2   = 1024 + 4096;  // [2][2048]
constexpr int    STATE_FLOATS = 9216;
constexpr size_t OFF_CNT  = 9216;         // unused; layout stability

// packed fp32 weight blobs (float4 counts)
constexpr size_t NA_F4  = (size_t)G * 24 * B;   // FF1: 2x3072x2048
constexpr size_t NB_F4  = (size_t)G * 32 * B;   // FF2: 2x4096x2048
constexpr size_t NC2_F4 = (size_t)128 * 4 * B;  // W2: 2048x512
constexpr size_t NC1_F4 = (size_t)128 * 5 * B;  // W1: 2560x512
constexpr size_t OFF_BLOBA  = 9344;
constexpr size_t OFF_BLOBB  = OFF_BLOBA  + NA_F4  * 4;
constexpr size_t OFF_BLOBC2 = OFF_BLOBB  + NB_F4  * 4;
constexpr size_t OFF_BLOBC1 = OFF_BLOBC2 + NC2_F4 * 4;
constexpr size_t WS_FLOATS  = OFF_BLOBC1 + NC1_F4 * 4;  // ~31.7M floats = ~127 MB

// FF1 register/LDS split: u = 0..NUR-1 in VGPRs, u = NUR..23 in LDS
constexpr int NUR_A = 8;
constexpr int NUL_A = 24 - NUR_A;   // 16 float4/thread -> 128 KB LDS

// ---------------- init ----------------
__global__ void init_state(float* ws) {
    int i = blockIdx.x * 256 + threadIdx.x;
    if (i < STATE_FLOATS) ws[i] = 0.f;
    if (i == 0) *(unsigned*)(ws + OFF_CNT) = 0u;
}

// ---------------- pack kernels (fp32, exact copies) ----------------
// FF blobs: thread mapping tid = c(0..7) + 8*jk + 16*s(0..31); col o = wg*8+c
// blob[(wg*nU+u)*B+tid] = float4 of 4 consecutive rows i0..i0+3 of column o.
__global__ void pack_ab(const float* __restrict__ J, const float* __restrict__ K,
                        float4* __restrict__ blob, int rpt, int nU)
{
    size_t id = (size_t)blockIdx.x * 256 + threadIdx.x;
    size_t total = (size_t)G * nU * B;
    if (id >= total) return;
    int tid = (int)(id & (B - 1));
    int u   = (int)((id >> 9) % nU);
    int wg  = (int)(id / ((size_t)B * nU));
    int c = tid & 7, jk = (tid >> 3) & 1, s = tid >> 4;
    int o = wg * 8 + c;
    int i0 = s * rpt + u * 4;
    const float* W = (jk ? K : J) + (size_t)i0 * 2048 + o;
    blob[id] = make_float4(W[0], W[2048], W[4096], W[6144]);
}

// Phase-C mapping: tid = c(0..3) + 4*s(0..127), col o = wg*4 + c
__global__ void pack_c(const float* __restrict__ W, float4* __restrict__ blob,
                       int fanOut, int rpt, int nU)
{
    size_t id = (size_t)blockIdx.x * 256 + threadIdx.x;
    size_t total = (size_t)128 * nU * B;
    if (id >= total) return;
    int tid = (int)(id & (B - 1));
    int u   = (int)((id >> 9) % nU);
    int wg  = (int)(id / ((size_t)B * nU));
    int c = tid & 3, s = tid >> 2;
    int o = wg * 4 + c;
    int i0 = s * rpt + u * 4;
    const float* p = W + (size_t)i0 * fanOut + o;
    blob[id] = make_float4(p[0], p[fanOut], p[2 * fanOut], p[3 * fanOut]);
}

// ---------------- device helpers ----------------
__device__ __forceinline__ float sigmoidf_(float d) { return 1.f / (1.f + __expf(-d)); }

// LDS pad: +4*((i/RPT)&7) floats; value-transparent, breaks s-stride bank aliasing.
template<int RPT>
__device__ __forceinline__ int pidx(int i) { return i + 4 * ((i / RPT) & 7); }

// FF phase: c = [p0 (n0) | hcur (2048)]; 8 cols/WG x {J,K}; updates h.
// ACCUMULATION ORDER = R1-unpacked: a0 over even rows (r=0,2,4,...),
// a1 over odd rows (r=1,3,5,...), each strictly ascending; acc = a0+a1.
template<int NU, int NUR, int RPT>
__device__ __forceinline__ void phase_ff(
    int wg, int tid, const float4 (&wreg)[NUR],
    const float4* __restrict__ ldsW,
    const float* __restrict__ Jb_, const float* __restrict__ Kb_,
    const float* __restrict__ p0, int n0,
    const float* __restrict__ hcur, float* __restrict__ hnxt,
    float* ldsC, float* red, float* jkb)
{
    const int s = tid >> 4;
    const int fanIn = n0 + 2048;
    for (int i = tid * 4; i < fanIn; i += B * 4) {
        float4 v = (i < n0) ? *(const float4*)(p0 + i)
                            : *(const float4*)(hcur + (i - n0));
        *(float4*)(ldsC + pidx<RPT>(i)) = v;
    }
    __syncthreads();
    const float* cp = ldsC + s * RPT + 4 * (s & 7);
    float a0 = 0.f, a1 = 0.f;
#pragma unroll
    for (int u = 0; u < NUR; ++u) {
        float4 cc = *(const float4*)(cp + 4 * u);
        float4 w = wreg[u];
        a0 = fmaf(cc.x, w.x, a0);   // r = 4u   (even chain)
        a1 = fmaf(cc.y, w.y, a1);   // r = 4u+1 (odd chain)
        a0 = fmaf(cc.z, w.z, a0);   // r = 4u+2
        a1 = fmaf(cc.w, w.w, a1);   // r = 4u+3
    }
#pragma unroll
    for (int u = NUR; u < NU; ++u) {
        float4 cc = *(const float4*)(cp + 4 * u);
        float4 w = ldsW[(u - NUR) * B + tid];
        a0 = fmaf(cc.x, w.x, a0);
        a1 = fmaf(cc.y, w.y, a1);
        a0 = fmaf(cc.z, w.z, a0);
        a1 = fmaf(cc.w, w.w, a1);
    }
    float acc = a0 + a1;
    acc += __shfl_xor(acc, 16);
    acc += __shfl_xor(acc, 32);
    const int wv = tid >> 6, lane = tid & 63;
    if (lane < 16) red[wv * 16 + lane] = acc;
    __syncthreads();
    if (tid < 16) {
        float d = 0.f;
#pragma unroll
        for (int w8 = 0; w8 < 8; ++w8) d += red[w8 * 16 + tid];
        const int cc = tid & 7;
        d += (tid >= 8) ? Kb_[wg * 8 + cc] : Jb_[wg * 8 + cc];
        jkb[tid] = sigmoidf_(d);
    }
    __syncthreads();
    if (tid < 8) {
        float j = jkb[tid], k = jkb[8 + tid];
        float h = ldsC[pidx<RPT>(n0 + wg * 8 + tid)];
        hnxt[wg * 8 + tid] = fmaf(j, 1.f - h, (1.f - k) * h);
    }
}

// Phase C: WGs 0..127 -> linear2(h2')+sigmoid -> out; WGs 128..255 -> linear1 -> x512
// ACCUMULATION ORDER = R1-unpacked: ONE accumulator, rows strictly ascending.
__device__ __forceinline__ void phase_c_lin(
    int wg, int tid, const float4 (&wreg)[5],
    const float* __restrict__ b2v, const float* __restrict__ b1v,
    const float* __restrict__ h2r, const float* __restrict__ X, int xrow,
    bool doOut, int outrow, bool doLin1,
    float* __restrict__ xb, float* __restrict__ ob, float* __restrict__ out_g,
    float* ldsC, float* red)
{
    const int s = tid >> 2;
    const int wv = tid >> 6, lane = tid & 63;
    if (wg < 128) {
        if (!doOut) return;
        for (int i = tid * 4; i < 2048; i += B * 4)
            *(float4*)(ldsC + pidx<16>(i)) = *(const float4*)(h2r + i);
        __syncthreads();
        const float* cp = ldsC + s * 16 + 4 * (s & 7);
        float acc = 0.f;
#pragma unroll
        for (int u = 0; u < 4; ++u) {
            float4 cc = *(const float4*)(cp + 4 * u);
            float4 w = wreg[u];
            acc = fmaf(cc.x, w.x, acc);
            acc = fmaf(cc.y, w.y, acc);
            acc = fmaf(cc.z, w.z, acc);
            acc = fmaf(cc.w, w.w, acc);
        }
        acc += __shfl_xor(acc, 4);  acc += __shfl_xor(acc, 8);
        acc += __shfl_xor(acc, 16); acc += __shfl_xor(acc, 32);
        if (lane < 4) red[wv * 4 + lane] = acc;
        __syncthreads();
        if (tid < 4) {
            float d = b2v[wg * 4 + tid];
#pragma unroll
            for (int w8 = 0; w8 < 8; ++w8) d += red[w8 * 4 + tid];
            float sg = sigmoidf_(d);
            ob[wg * 4 + tid] = sg;
            out_g[(size_t)outrow * 512 + wg * 4 + tid] = sg;
        }
    } else {
        if (!doLin1) return;
        const int wg2 = wg - 128;
        const float* Xr = X + (size_t)xrow * 512;
        for (int i = tid * 4; i < 2560; i += B * 4) {
            float4 v = (i < 2048) ? *(const float4*)(h2r + i)
                                  : *(const float4*)(Xr + (i - 2048));
            *(float4*)(ldsC + pidx<20>(i)) = v;
        }
        __syncthreads();
        const float* cp = ldsC + s * 20 + 4 * (s & 7);
        float acc = 0.f;
#pragma unroll
        for (int u = 0; u < 5; ++u) {
            float4 cc = *(const float4*)(cp + 4 * u);
            float4 w = wreg[u];
            acc = fmaf(cc.x, w.x, acc);
            acc = fmaf(cc.y, w.y, acc);
            acc = fmaf(cc.z, w.z, acc);
            acc = fmaf(cc.w, w.w, acc);
        }
        acc += __shfl_xor(acc, 4);  acc += __shfl_xor(acc, 8);
        acc += __shfl_xor(acc, 16); acc += __shfl_xor(acc, 32);
        if (lane < 4) red[wv * 4 + lane] = acc;
        __syncthreads();
        if (tid < 4) {
            float d = b1v[wg2 * 4 + tid];
#pragma unroll
            for (int w8 = 0; w8 < 8; ++w8) d += red[w8 * 4 + tid];
            xb[wg2 * 4 + tid] = d;   // linear1 has NO activation
        }
    }
}

// ---------------- persistent cooperative kernel ----------------
__global__ void __launch_bounds__(B, 2)
rnn_kernel(const float* __restrict__ X,
           const float* __restrict__ b1,
           const float* __restrict__ J1b, const float* __restrict__ K1b,
           const float* __restrict__ J2b, const float* __restrict__ K2b,
           const float* __restrict__ b2,
           float* __restrict__ out_g, float* __restrict__ ws)
{
    cg::grid_group grid = cg::this_grid();
    const int wg = blockIdx.x, tid = threadIdx.x;
    __shared__ float4 ldsW[NUL_A * B];   // 128 KB: FF1 weights u=8..23
    __shared__ float ldsC[4160];
    __shared__ float red[128];
    __shared__ float jkb[16];

    float* xb  = ws + OFF_X512;
    float* ob  = ws + OFF_OUT;
    float* h1b = ws + OFF_H1;
    float* h2b = ws + OFF_H2;

    // ---- load weights: FF2 + phase-C + FF1[u<8] into VGPRs; FF1[u>=8] into LDS ----
    float4 wA[NUR_A], wB[32], wC[5];
    {
        const float4* bp = (const float4*)(ws + OFF_BLOBA) + (size_t)wg * 24 * B + tid;
#pragma unroll
        for (int u = 0; u < NUR_A; ++u) wA[u] = bp[(size_t)u * B];
#pragma unroll
        for (int u = NUR_A; u < 24; ++u) ldsW[(u - NUR_A) * B + tid] = bp[(size_t)u * B];
    }
    {
        const float4* bp = (const float4*)(ws + OFF_BLOBB) + (size_t)wg * 32 * B + tid;
#pragma unroll
        for (int u = 0; u < 32; ++u) wB[u] = bp[(size_t)u * B];
    }
    if (wg < 128) {
        const float4* bp = (const float4*)(ws + OFF_BLOBC2) + (size_t)wg * 4 * B + tid;
#pragma unroll
        for (int u = 0; u < 4; ++u) wC[u] = bp[(size_t)u * B];
        wC[4] = make_float4(0.f, 0.f, 0.f, 0.f);
    } else {
        const float4* bp = (const float4*)(ws + OFF_BLOBC1) + (size_t)(wg - 128) * 5 * B + tid;
#pragma unroll
        for (int u = 0; u < 5; ++u) wC[u] = bp[(size_t)u * B];
    }

    // pre-loop: x512 for t=0 (h2 = 0 from init kernel); no out yet
    phase_c_lin(wg, tid, wC, b2, b1, h2b, X, 0, false, 0, true,
                xb, ob, out_g, ldsC, red);
    grid.sync();

    for (int t = 0; t < TSTEPS; ++t) {
        const int cur = t & 1, nxt = cur ^ 1;
        // FF1: c = [x512 | out | h1cur] -> h1nxt
        phase_ff<24, NUR_A, 96>(wg, tid, wA, ldsW, J1b, K1b,
                                ws /* [x512|out] contiguous */, 1024,
                                h1b + cur * 2048, h1b + nxt * 2048, ldsC, red, jkb);
        grid.sync();
        // FF2: c = [h1nxt | h2cur] -> h2nxt (all weights in registers)
        phase_ff<32, 32, 128>(wg, tid, wB, ldsW, J2b, K2b,
                              h1b + nxt * 2048, 2048,
                              h2b + cur * 2048, h2b + nxt * 2048, ldsC, red, jkb);
        grid.sync();
        // linear2(h2nxt) -> out(t) ; linear1([h2nxt, X[t+1]]) -> x512(t+1)
        phase_c_lin(wg, tid, wC, b2, b1, h2b + nxt * 2048, X, t + 1,
                    true, t, (t + 1 < TSTEPS), xb, ob, out_g, ldsC, red);
        grid.sync();
    }
}

// ---------------- host ----------------
extern "C" void kernel_launch(void* const* d_in, const int* in_sizes, int n_in,
                              void* d_out, int out_size, void* d_ws, size_t ws_size,
                              hipStream_t stream)
{
    const float* X   = (const float*)d_in[0];
    const float* W1  = (const float*)d_in[1];
    const float* b1  = (const float*)d_in[2];
    const float* J1W = (const float*)d_in[3];
    const float* J1b = (const float*)d_in[4];
    const float* K1W = (const float*)d_in[5];
    const float* K1b = (const float*)d_in[6];
    const float* J2W = (const float*)d_in[7];
    const float* J2b = (const float*)d_in[8];
    const float* K2W = (const float*)d_in[9];
    const float* K2b = (const float*)d_in[10];
    const float* W2  = (const float*)d_in[11];
    const float* b2  = (const float*)d_in[12];
    float* out = (float*)d_out;
    float* ws  = (float*)d_ws;

    init_state<<<dim3((STATE_FLOATS + 255) / 256), dim3(256), 0, stream>>>(ws);
    pack_ab<<<dim3((unsigned)(NA_F4 / 256)), dim3(256), 0, stream>>>(
        J1W, K1W, (float4*)(ws + OFF_BLOBA), 96, 24);
    pack_ab<<<dim3((unsigned)(NB_F4 / 256)), dim3(256), 0, stream>>>(
        J2W, K2W, (float4*)(ws + OFF_BLOBB), 128, 32);
    pack_c<<<dim3((unsigned)(NC2_F4 / 256)), dim3(256), 0, stream>>>(
        W2, (float4*)(ws + OFF_BLOBC2), 512, 16, 4);
    pack_c<<<dim3((unsigned)(NC1_F4 / 256)), dim3(256), 0, stream>>>(
        W1, (float4*)(ws + OFF_BLOBC1), 512, 20, 5);

    void* args[] = { (void*)&X, (void*)&b1,
                     (void*)&J1b, (void*)&K1b, (void*)&J2b, (void*)&K2b,
                     (void*)&b2, (void*)&out, (void*)&ws };
    hipLaunchCooperativeKernel((const void*)rnn_kernel, dim3(G), dim3(B),
                               args, 0, stream);
}